// Round 17
// baseline (351.788 us; speedup 1.0000x reference)
//
#include <hip/hip_runtime.h>
#include <math.h>

#define N_    16
#define CIN_  16
#define T_    512
#define V_    200
#define K_    3
#define COUT_ 64
#define H_    64
#define G_    256  // 4*H

// Workspace layout (float offsets):
//   a  : [0, 600)                 a[k][v] = sum_w A[k,v,w] / V
//   sa : [640, 643)               sa[k] = sum_{v,w} A[k,v,w] / V
//   xa : [1024, 1024+16*512*48)   xa[n][t][k*16+ci]
//   xW : [WS_XW, +512*16*256)     xW[t][n][g]  (gate pre-activations, input side)
#define WS_A  0
#define WS_SA 640
#define WS_XA 1024
#define WS_XW (WS_XA + N_ * T_ * K_ * CIN_)

typedef __attribute__((ext_vector_type(4))) float f32x4;

// fast activations: v_exp_f32-based, ~1e-6 rel err, saturate correctly
__device__ __forceinline__ float fast_sig(float x) {
    return __builtin_amdgcn_rcpf(1.f + __expf(-x));
}
__device__ __forceinline__ float fast_tanh(float x) {
    return fmaf(-2.f, __builtin_amdgcn_rcpf(1.f + __expf(2.f * x)), 1.f);
}

// ---------------------------------------------------------------------------
// Kernel 1 (fused prep): blocks [0, NCOPY) copy A->out[16:] (blocks 0-2 also
// compute a[k][v]); blocks NCOPY+k (k=0..2) reduce A[k] to sa[k].
#define NCOPY ((K_ * V_ * V_ + 255) / 256)
__global__ __launch_bounds__(256) void prep_kernel(const float* __restrict__ A,
                                                   float* __restrict__ out,
                                                   float* __restrict__ ws) {
    int b = blockIdx.x;
    if (b < NCOPY) {
        int tid = b * 256 + threadIdx.x;
        if (tid < K_ * V_ * V_) out[16 + tid] = A[tid];
        if (tid < K_ * V_) {
            const float* row = A + (long)tid * V_;
            float s = 0.f;
            for (int w = 0; w < V_; ++w) s += row[w];
            ws[WS_A + tid] = s * (1.0f / V_);
        }
    } else {
        int k = b - NCOPY;                      // 0..2
        const float* Ak = A + (long)k * V_ * V_;
        float s = 0.f;
        for (int i = threadIdx.x; i < V_ * V_; i += 256) s += Ak[i];
        #pragma unroll
        for (int m = 1; m < 64; m <<= 1) s += __shfl_xor(s, m);
        __shared__ float red[4];
        if ((threadIdx.x & 63) == 0) red[threadIdx.x >> 6] = s;
        __syncthreads();
        if (threadIdx.x == 0)
            ws[WS_SA + k] = (red[0] + red[1] + red[2] + red[3]) * (1.0f / V_);
    }
}

// ---------------------------------------------------------------------------
// Kernel 2 (tiled xa): xa[n][t][k*16+ci] = sum_v x[n][ci][t][v] * a[k][v]
// One block per (n, ci, 64-t chunk) = 2048 blocks.
#define TT 64
#define PADV 204
__global__ __launch_bounds__(256) void xa_kernel(const float* __restrict__ x,
                                                 float* __restrict__ ws) {
    __shared__ __align__(16) float xt[TT * PADV];
    __shared__ __align__(16) float aS[K_ * V_];
    int tid = threadIdx.x;
    int b = blockIdx.x;
    int tchunk = b & 7;
    int ci = (b >> 3) & 15;
    int n = b >> 7;
    int t0 = tchunk * TT;

    for (int i = tid; i < K_ * V_; i += 256) aS[i] = ws[WS_A + i];

    const float4* xg4 =
        (const float4*)(x + ((long)(n * CIN_ + ci) * T_ + t0) * V_);
    for (int j = tid; j < TT * (V_ / 4); j += 256) {
        float4 v = xg4[j];
        int t = j / (V_ / 4), v4 = (j % (V_ / 4)) * 4;
        *(float4*)(xt + t * PADV + v4) = v;
    }
    __syncthreads();

    int t_local = tid & 63;
    int k = tid >> 6;            // waves 0..2 active, wave 3 idle
    if (k < K_) {
        const float* xr = xt + t_local * PADV;
        const float* ar = aS + k * V_;
        float a0 = 0.f, a1 = 0.f, a2 = 0.f, a3 = 0.f;
        #pragma unroll 5
        for (int v4 = 0; v4 < V_; v4 += 4) {
            float4 xv = *(const float4*)(xr + v4);
            float4 av = *(const float4*)(ar + v4);   // wave-uniform broadcast
            a0 = fmaf(xv.x, av.x, a0);
            a1 = fmaf(xv.y, av.y, a1);
            a2 = fmaf(xv.z, av.z, a2);
            a3 = fmaf(xv.w, av.w, a3);
        }
        float s = (a0 + a1) + (a2 + a3);
        ws[WS_XA + ((long)n * T_ + (t0 + t_local)) * (K_ * CIN_) + k * CIN_ + ci] = s;
    }
}

// ---------------------------------------------------------------------------
// Kernel 3 (fused seq + input-gate GEMM): ONE block per t (512 blocks).
__global__ __launch_bounds__(256) void seqgates_kernel(
    const float* __restrict__ W_gcn, const float* __restrict__ b_gcn,
    const float* __restrict__ W_ih, const float* __restrict__ b_ih,
    const float* __restrict__ b_hh, float* __restrict__ ws) {
    int t = blockIdx.x;
    int tid = threadIdx.x;
    __shared__ float xaS[N_][K_ * CIN_];
    __shared__ __align__(16) float seqS[N_][COUT_];
    __shared__ float saS[K_];

    if (tid < K_) saS[tid] = ws[WS_SA + tid];
    #pragma unroll
    for (int r = 0; r < 3; ++r) {
        int i = tid + r * 256;
        if (i < N_ * K_ * CIN_) {
            int n = i / (K_ * CIN_), kc = i % (K_ * CIN_);
            xaS[n][kc] = ws[WS_XA + (long)(n * T_ + t) * (K_ * CIN_) + kc];
        }
    }
    __syncthreads();

    // Phase 1: thread (n = tid>>4, c0 = (tid&15)*4) computes 4 seq entries.
    {
        int n = tid >> 4, c0 = (tid & 15) * 4;
        #pragma unroll
        for (int cc = 0; cc < 4; ++cc) {
            int c = c0 + cc;
            float s = 0.f;
            #pragma unroll
            for (int k = 0; k < K_; ++k) {
                s = fmaf(b_gcn[k * COUT_ + c], saS[k], s);
                const float* wrow = W_gcn + (long)(k * COUT_ + c) * CIN_;
                #pragma unroll
                for (int ci = 0; ci < CIN_; ++ci)
                    s = fmaf(wrow[ci], xaS[n][k * CIN_ + ci], s);
            }
            seqS[n][c] = s;
        }
    }
    __syncthreads();

    // Phase 2: thread g: 16 accumulators over n; W_ih row streamed as float4.
    {
        int g = tid;
        float acc[N_];
        #pragma unroll
        for (int n = 0; n < N_; ++n) acc[n] = 0.f;
        const float4* wrow4 = (const float4*)(W_ih + (long)g * H_);
        #pragma unroll
        for (int c4 = 0; c4 < H_ / 4; ++c4) {
            float4 w4 = wrow4[c4];
            #pragma unroll
            for (int n = 0; n < N_; ++n) {
                float4 s4 = ((const float4*)seqS[n])[c4];  // LDS broadcast
                acc[n] = fmaf(w4.x, s4.x, acc[n]);
                acc[n] = fmaf(w4.y, s4.y, acc[n]);
                acc[n] = fmaf(w4.z, s4.z, acc[n]);
                acc[n] = fmaf(w4.w, s4.w, acc[n]);
            }
        }
        float bias = b_ih[g] + b_hh[g];
        #pragma unroll
        for (int n = 0; n < N_; ++n)
            ws[WS_XW + (long)(t * N_ + n) * G_ + g] = acc[n] + bias;
    }
}

// ---------------------------------------------------------------------------
// Kernel 4: sequential LSTM scan — chain-shortened (R13 structure) with
// RESIDENT weights (asm WLOAD + amdgpu_waves_per_eu(1,1), proven in R16:
// VGPR 44->132). R16 falsified the weight-stream theory (resident weights:
// 260->256.6us only); the cost is the serial sync/exchange chain. This
// removes the gbuf LDS roundtrip + one barrier (~230cy) for 3 pipelined
// shuffles (~80cy):
//   wave w owns j in [16w,16w+16); lane = 16*ty + jj. Each lane computes its
//   own gate dot + its own nonlinearity (branchless sigma/tanh select);
//   i/f/g/o combined via 3 intra-wave shuffles; ty=0 lanes carry (c,h) and
//   write h to double-buffered hS; ONE barrier per step.
__global__ __attribute__((amdgpu_waves_per_eu(1, 1)))
__launch_bounds__(256) void lstm_kernel(
    const float* __restrict__ W_hh, const float* __restrict__ W_fc,
    const float* __restrict__ b_fc, const float* __restrict__ ws,
    float* __restrict__ out) {
    int n = blockIdx.x;
    int tid = threadIdx.x;
    int w = tid >> 6;
    int lane = tid & 63;
    int ty = lane >> 4;           // gate type (torch order i,f,g,o)
    int jj = lane & 15;           // j within the wave's slice

    // One-time, resident load of W_hh row (ty*64 + 16w + jj).
    const f32x4* wr = (const f32x4*)(W_hh + (long)(ty * 64 + 16 * w + jj) * H_);
    f32x4 w0, w1, w2, w3, w4, w5, w6, w7, w8, w9, w10, w11, w12, w13, w14, w15;
    #define WLOAD(i) \
        asm volatile("global_load_dwordx4 %0, %1, off" : "=v"(w##i) : "v"(wr + i));
    WLOAD(0)  WLOAD(1)  WLOAD(2)  WLOAD(3)
    WLOAD(4)  WLOAD(5)  WLOAD(6)  WLOAD(7)
    WLOAD(8)  WLOAD(9)  WLOAD(10) WLOAD(11)
    WLOAD(12) WLOAD(13) WLOAD(14) WLOAD(15)
    #undef WLOAD
    asm volatile("s_waitcnt vmcnt(0)" ::: "memory");

    // lane-constant activation params: act = m*sigma(s*gate) + b
    float s_act = (ty == 2) ? 2.f : 1.f;
    float m_act = (ty == 2) ? 2.f : 1.f;
    float b_act = (ty == 2) ? -1.f : 0.f;

    __shared__ __align__(16) float hS[2][H_];
    if (tid < H_) hS[0][tid] = 0.f;
    float ccell = 0.f;            // live in ty==0 lanes
    __syncthreads();

    const float* xw = ws + WS_XW + (long)n * G_ + (ty * 64 + 16 * w + jj);
    float x0 = xw[0];
    float x1 = xw[(long)N_ * G_];

    for (int t = 0; t < T_; ++t) {
        int p = t & 1;
        float gate = x0;
        x0 = x1;
        if (t + 2 < T_) x1 = xw[(long)(t + 2) * N_ * G_];

        // dot(W row, h): h via uniform-address b128 broadcast from hS[p],
        // weights in resident VGPRs, 4 accumulators for ILP.
        float a0 = 0.f, a1 = 0.f, a2 = 0.f, a3 = 0.f;
        const float4* h4 = (const float4*)hS[p];
        #define DOT4(i)                            \
            {                                      \
                float4 hv = h4[i];                 \
                a0 = fmaf(w##i[0], hv.x, a0);      \
                a1 = fmaf(w##i[1], hv.y, a1);      \
                a2 = fmaf(w##i[2], hv.z, a2);      \
                a3 = fmaf(w##i[3], hv.w, a3);      \
            }
        DOT4(0)  DOT4(1)  DOT4(2)  DOT4(3)
        DOT4(4)  DOT4(5)  DOT4(6)  DOT4(7)
        DOT4(8)  DOT4(9)  DOT4(10) DOT4(11)
        DOT4(12) DOT4(13) DOT4(14) DOT4(15)
        #undef DOT4
        gate += (a0 + a1) + (a2 + a3);

        // own nonlinearity, then gather the other 3 types in-wave
        float act = fmaf(m_act, fast_sig(s_act * gate), b_act);
        float fv = __shfl(act, 16 + jj);
        float gv = __shfl(act, 32 + jj);
        float ov = __shfl(act, 48 + jj);
        if (ty == 0) {
            ccell = fmaf(fv, ccell, act * gv);       // act == iv here
            float h = ov * fast_tanh(ccell);
            hS[p ^ 1][16 * w + jj] = h;
        }
        __syncthreads();          // the ONLY barrier per step
    }

    // T_ even -> final h in hS[0]
    if (tid < H_) {
        float pv = hS[0][tid] * W_fc[tid];
        #pragma unroll
        for (int m = 1; m < 64; m <<= 1) pv += __shfl_xor(pv, m);
        if (tid == 0) out[n] = pv + b_fc[0];
    }
}

// ---------------------------------------------------------------------------
extern "C" void kernel_launch(void* const* d_in, const int* in_sizes, int n_in,
                              void* d_out, int out_size, void* d_ws, size_t ws_size,
                              hipStream_t stream) {
    const float* x     = (const float*)d_in[0];
    const float* A     = (const float*)d_in[1];
    const float* W_gcn = (const float*)d_in[2];
    const float* b_gcn = (const float*)d_in[3];
    const float* W_ih  = (const float*)d_in[4];
    const float* W_hh  = (const float*)d_in[5];
    const float* b_ih  = (const float*)d_in[6];
    const float* b_hh  = (const float*)d_in[7];
    const float* W_fc  = (const float*)d_in[8];
    const float* b_fc  = (const float*)d_in[9];
    float* out = (float*)d_out;
    float* ws  = (float*)d_ws;

    // 1) fused: copy A->out, a[k][v], sa[k]
    prep_kernel<<<NCOPY + K_, 256, 0, stream>>>(A, out, ws);
    // 2) tiled xa (one block per (n, ci, 64-t chunk))
    xa_kernel<<<N_ * CIN_ * (T_ / TT), 256, 0, stream>>>(x, ws);
    // 3) fused seq + input-side gate GEMM (one block per t)
    seqgates_kernel<<<T_, 256, 0, stream>>>(W_gcn, b_gcn, W_ih, b_ih, b_hh, ws);
    // 4) chain-shortened sequential LSTM scan + final FC
    lstm_kernel<<<N_, 256, 0, stream>>>(W_hh, W_fc, b_fc, ws, out);
}